// Round 1
// baseline (770.348 us; speedup 1.0000x reference)
//
#include <hip/hip_runtime.h>
#include <math.h>

typedef __attribute__((ext_vector_type(8))) short short8;
typedef __attribute__((ext_vector_type(4))) float f32x4;

#define INF 3.0e38f
#define BN_EPS 1e-5f

// ---- x-bucket grid for 3-NN (exact; bucket walk with provable stop bound) --
#define NB 1024            // buckets per batch along x
#define XMIN (-64.0f)
#define XMAX (64.0f)
#define BW 0.125f          // bucket width = 128/NB
#define INVW 8.0f

__device__ __forceinline__ unsigned short f2bf(float x) {
    union { float f; unsigned u; } v; v.f = x;
    unsigned r = v.u + 0x7FFF + ((v.u >> 16) & 1);   // RNE
    return (unsigned short)(r >> 16);
}
__device__ __forceinline__ float bf2f(unsigned short u) {
    return __uint_as_float(((unsigned)u) << 16);
}

// --------------------------------------------------------- grid: histogram --
__global__ __launch_bounds__(256) void hist_kernel(
    const float* __restrict__ kn, const int* __restrict__ kcnt,
    int B, int M, int* __restrict__ cnt)
{
    int j = blockIdx.x * 256 + threadIdx.x;
    if (j >= M) return;
    int cum = 0, bb = 0;
    for (int i = 0; i < B; i++) { int c = kcnt[i]; if (j >= cum) bb = i; cum += c; }
    float x = kn[j * 3];
    int bi = (int)((x - XMIN) * INVW);
    bi = min(max(bi, 0), NB - 1);
    atomicAdd(&cnt[bb * NB + bi], 1);
}

// ------------------------------------------- grid: exclusive scan (T<=4096) --
__global__ __launch_bounds__(1024) void scan_kernel(
    const int* __restrict__ cnt, int* __restrict__ bs, int* __restrict__ cur, int T)
{
    __shared__ int ts[1024];
    int tid = threadIdx.x;
    int base = tid * 4;
    int v0 = 0, v1 = 0, v2 = 0, v3 = 0;
    if (base + 0 < T) v0 = cnt[base + 0];
    if (base + 1 < T) v1 = cnt[base + 1];
    if (base + 2 < T) v2 = cnt[base + 2];
    if (base + 3 < T) v3 = cnt[base + 3];
    int s = v0 + v1 + v2 + v3;
    ts[tid] = s;
    __syncthreads();
    for (int off = 1; off < 1024; off <<= 1) {
        int t = (tid >= off) ? ts[tid - off] : 0;
        __syncthreads();
        ts[tid] += t;
        __syncthreads();
    }
    int ex = ts[tid] - s;
    if (base + 0 < T) { bs[base + 0] = ex; cur[base + 0] = ex; } ex += v0;
    if (base + 1 < T) { bs[base + 1] = ex; cur[base + 1] = ex; } ex += v1;
    if (base + 2 < T) { bs[base + 2] = ex; cur[base + 2] = ex; } ex += v2;
    if (base + 3 < T) { bs[base + 3] = ex; cur[base + 3] = ex; } ex += v3;
    if (tid == ((T - 1) >> 2)) bs[T] = ts[tid];
}

// ----------------------------------------------------------- grid: scatter --
__global__ __launch_bounds__(256) void scatter_kernel(
    const float* __restrict__ kn, const int* __restrict__ kcnt,
    int B, int M, int* __restrict__ cur, float4* __restrict__ scat)
{
    int j = blockIdx.x * 256 + threadIdx.x;
    if (j >= M) return;
    int cum = 0, bb = 0;
    for (int i = 0; i < B; i++) { int c = kcnt[i]; if (j >= cum) bb = i; cum += c; }
    float x = kn[j * 3], y = kn[j * 3 + 1], z = kn[j * 3 + 2];
    int bi = (int)((x - XMIN) * INVW);
    bi = min(max(bi, 0), NB - 1);
    int pos = atomicAdd(&cur[bb * NB + bi], 1);
    scat[pos] = make_float4(x, y, z, __int_as_float(j));
}

// ---------------------------------------------------------------- 3-NN ----
// Bucket-walk exact 3-NN. 4 lanes/point: roles 0,1 walk left (stride 2),
// roles 2,3 walk right. One pass; u64 (f32bits<<32|idx) lex keys => selection
// identical to lax.top_k (incl. tie -> lower index). Stop bound: all positions
// beyond the current one lie in buckets at least as far, so their |dx| >=
// |clamp(x)-ux| - BW; stop when that bound squared >= Bnd (group-tightened
// 3rd-best, which is >= true union 3rd-best at all times => exact).
__global__ __launch_bounds__(256) void knn3_grid_kernel(
    const float* __restrict__ unk, const int* __restrict__ ucnt,
    const int* __restrict__ bs, const float4* __restrict__ scat,
    int B, float* __restrict__ wgt, int* __restrict__ idxo)
{
    __shared__ unsigned long long mk[64][4][3];

    int tid = threadIdx.x;
    int lp = tid >> 2;          // local point 0..63
    int role = tid & 3;
    int pbase = blockIdx.x * 64;
    int p = pbase + lp;

    int cum = 0, bb = 0;
    for (int i = 0; i < B; i++) { int c = ucnt[i]; if (pbase >= cum) bb = i; cum += c; }

    float ux = unk[p * 3 + 0], uy = unk[p * 3 + 1], uz = unk[p * 3 + 2];

    int kst = bs[bb * NB];
    int ken = bs[(bb + 1) * NB];
    int bq = (int)((ux - XMIN) * INVW);
    bq = min(max(bq, 0), NB - 1);
    int sp = bs[bb * NB + bq];  // first position of query bucket

    bool left = (role < 2);
    int sub = role & 1;
    int pos = left ? (sp - 1 - sub) : (sp + sub);
    int step = left ? -2 : 2;

    unsigned long long k0 = ~0ULL, k1 = ~0ULL, k2 = ~0ULL;
    auto insK = [&](unsigned long long k) {
        bool c0 = k < k0;
        unsigned long long t0 = c0 ? k : k0;
        unsigned long long t1 = c0 ? k0 : k;
        bool c1 = t1 < k1;
        unsigned long long u0 = c1 ? t1 : k1;
        unsigned long long u1 = c1 ? k1 : t1;
        k0 = t0; k1 = u0;
        k2 = u1 < k2 ? u1 : k2;
    };

    float Bnd = INF;
    bool alive = left ? (pos >= kst) : (pos < ken);
    int it = 0;
    while (__any(alive)) {
        if (alive) {
            float4 f = scat[pos];
            float dx = f.x - ux, dy = f.y - uy, dz = f.z - uz;
            float e = __builtin_fmaf(dx, dx, __builtin_fmaf(dy, dy, dz * dz));
            if (e <= Bnd) {   // inclusive: exact ties resolved by lex key
                insK(((unsigned long long)__float_as_uint(e) << 32) |
                     (unsigned)__float_as_int(f.w));
                Bnd = fminf(Bnd, __uint_as_float((unsigned)(k2 >> 32)));
            }
            float xc = left ? fmaxf(f.x, XMIN) : fminf(f.x, XMAX);
            float t = (left ? (ux - xc) : (xc - ux)) - BW;
            if (t > 0.0f && t * t >= Bnd) alive = false;
            pos += step;
            if (left ? (pos < kst) : (pos >= ken)) alive = false;
        }
        if ((++it & 7) == 0) {   // tighten bound across the 4-lane group
            float b = fminf(Bnd, __shfl_xor(Bnd, 1));
            Bnd = fminf(b, __shfl_xor(b, 2));
        }
    }

    mk[lp][role][0] = k0; mk[lp][role][1] = k1; mk[lp][role][2] = k2;
    __syncthreads();

    if (tid < 64) {
        unsigned long long a0 = ~0ULL, a1 = ~0ULL, a2 = ~0ULL;
        auto ins2 = [&](unsigned long long k) {
            bool c0 = k < a0;
            unsigned long long t0 = c0 ? k : a0;
            unsigned long long t1 = c0 ? a0 : k;
            bool c1 = t1 < a1;
            unsigned long long u0 = c1 ? t1 : a1;
            unsigned long long u1 = c1 ? a1 : t1;
            a0 = t0; a1 = u0;
            a2 = u1 < a2 ? u1 : a2;
        };
#pragma unroll
        for (int r = 0; r < 4; r++)
#pragma unroll
            for (int kk = 0; kk < 3; kk++)
                ins2(mk[tid][r][kk]);

        float dd0 = __uint_as_float((unsigned)(a0 >> 32));
        float dd1 = __uint_as_float((unsigned)(a1 >> 32));
        float dd2 = __uint_as_float((unsigned)(a2 >> 32));
        float r0 = 1.0f / (dd0 + 1e-8f);
        float r1 = 1.0f / (dd1 + 1e-8f);
        float r2 = 1.0f / (dd2 + 1e-8f);
        float rs = 1.0f / (r0 + r1 + r2);
        int pp = pbase + tid;
        wgt[pp * 3 + 0] = r0 * rs;
        wgt[pp * 3 + 1] = r1 * rs;
        wgt[pp * 3 + 2] = r2 * rs;
        idxo[pp * 3 + 0] = (int)(unsigned)a0;
        idxo[pp * 3 + 1] = (int)(unsigned)a1;
        idxo[pp * 3 + 2] = (int)(unsigned)a2;
    }
}

// ------------------------------------------------ weight fp32->bf16 conv --
__global__ __launch_bounds__(256) void wconv_kernel(
    const float* __restrict__ W1, const float* __restrict__ W2,
    unsigned short* __restrict__ W1b, unsigned short* __restrict__ W2b,
    int n1, int n2)
{
    int i = blockIdx.x * 256 + threadIdx.x;
    if (i < n1) W1b[i] = f2bf(W1[i]);
    int j = i - n1;
    if (j >= 0 && j < n2) W2b[j] = f2bf(W2[j]);
}

// -------------------------------------------------------- bf16 MFMA GEMM --
// C[N,256] = A[N,K] x W[256,K]^T.  128x128 tile, BK=32, 16x16x32 MFMA.
// MODE 2 (gemm1): A materialized on the fly in staging (interp cols 0..255
//   gathered from kfeat via wgt/idx; ufeat cols 256..383). C stored as BF16
//   (h1) — BN1 stats come from fp32 accumulators, exact.
// MODE 1 (gemm2): A = relu(h1_bf16*scale+shift) -> bf16; scale/shift computed
//   in a 256-thread LDS prologue from raw BN sums (bn_finalize folded in).
//   C stored fp32 (h2).
// Fused epilogue: per-block column sum/sumsq of C -> global atomics.
template <int K, int MODE>
__global__ __launch_bounds__(256) void gemm_bf16_kernel(
    const void* __restrict__ Aa, const float* __restrict__ ufeat,
    const unsigned short* __restrict__ W,
    const float* __restrict__ wgt, const int* __restrict__ idxv,
    const float* __restrict__ bnsum, const float* __restrict__ bnsq,
    const float* __restrict__ bng, const float* __restrict__ bnb, float invN,
    void* __restrict__ Cv, float* __restrict__ gsum, float* __restrict__ gsq)
{
    __shared__ unsigned short As[128 * 40];
    __shared__ unsigned short Bs[128 * 40];
    __shared__ float colsum[128];
    __shared__ float colsq[128];
    __shared__ float sc[256], sh[256];

    int tid = threadIdx.x;
    int w = tid >> 6, lane = tid & 63;
    int r = w >> 1, cq = w & 1;
    int m16 = lane & 15, q = lane >> 4;
    int bm = blockIdx.x * 128, bn = blockIdx.y * 128;

    if (MODE == 1) {            // fold bn_finalize: per-channel scale/shift
        float mean = bnsum[tid] * invN;
        float var = bnsq[tid] * invN - mean * mean;
        float scv = bng[tid] * rsqrtf(var + BN_EPS);
        sc[tid] = scv;
        sh[tid] = bnb[tid] - mean * scv;
    }

    // per-thread staging slots: rows srow, srow+64 with fixed 8-ch chunk kc
    int srow = tid >> 2;
    int kc = (tid & 3) * 8;
    float w0a[2], w1a[2], w2a[2];
    int j0a[2], j1a[2], j2a[2];
    if (MODE == 2) {
#pragma unroll
        for (int t = 0; t < 2; t++) {
            int pp = bm + srow + 64 * t;
            w0a[t] = wgt[pp * 3 + 0]; w1a[t] = wgt[pp * 3 + 1]; w2a[t] = wgt[pp * 3 + 2];
            j0a[t] = idxv[pp * 3 + 0]; j1a[t] = idxv[pp * 3 + 1]; j2a[t] = idxv[pp * 3 + 2];
        }
    }

    f32x4 acc[4][4];
#pragma unroll
    for (int i = 0; i < 4; i++)
#pragma unroll
        for (int j = 0; j < 4; j++) acc[i][j] = (f32x4){0.f, 0.f, 0.f, 0.f};

#pragma unroll
    for (int k0 = 0; k0 < K; k0 += 32) {
        __syncthreads();
#pragma unroll
        for (int t = 0; t < 2; t++) {
            int row = srow + 64 * t;
            int c = k0 + kc;
            ushort4 o0, o1;
            if (MODE == 2) {
                if (c < 256) {          // interp cols (compile-time per iter)
                    const float* f0 = (const float*)Aa + (size_t)j0a[t] * 256 + c;
                    const float* f1 = (const float*)Aa + (size_t)j1a[t] * 256 + c;
                    const float* f2 = (const float*)Aa + (size_t)j2a[t] * 256 + c;
                    float4 x0 = *(const float4*)f0, x1 = *(const float4*)(f0 + 4);
                    float4 y0 = *(const float4*)f1, y1 = *(const float4*)(f1 + 4);
                    float4 z0 = *(const float4*)f2, z1 = *(const float4*)(f2 + 4);
                    float W0 = w0a[t], W1 = w1a[t], W2 = w2a[t];
                    o0.x = f2bf(x0.x * W0 + y0.x * W1 + z0.x * W2);
                    o0.y = f2bf(x0.y * W0 + y0.y * W1 + z0.y * W2);
                    o0.z = f2bf(x0.z * W0 + y0.z * W1 + z0.z * W2);
                    o0.w = f2bf(x0.w * W0 + y0.w * W1 + z0.w * W2);
                    o1.x = f2bf(x1.x * W0 + y1.x * W1 + z1.x * W2);
                    o1.y = f2bf(x1.y * W0 + y1.y * W1 + z1.y * W2);
                    o1.z = f2bf(x1.z * W0 + y1.z * W1 + z1.z * W2);
                    o1.w = f2bf(x1.w * W0 + y1.w * W1 + z1.w * W2);
                } else {                // ufeat cols
                    const float* fu = ufeat + (size_t)(bm + row) * 128 + (c - 256);
                    float4 u0 = *(const float4*)fu, u1 = *(const float4*)(fu + 4);
                    o0.x = f2bf(u0.x); o0.y = f2bf(u0.y);
                    o0.z = f2bf(u0.z); o0.w = f2bf(u0.w);
                    o1.x = f2bf(u1.x); o1.y = f2bf(u1.y);
                    o1.z = f2bf(u1.z); o1.w = f2bf(u1.w);
                }
            } else {                    // MODE 1: bn+relu+bf16 from bf16 h1
                const unsigned short* Ab = (const unsigned short*)Aa;
                ushort4 h0 = *(const ushort4*)(Ab + (size_t)(bm + row) * K + c);
                ushort4 h1v = *(const ushort4*)(Ab + (size_t)(bm + row) * K + c + 4);
                float4 s0 = *(const float4*)&sc[c];
                float4 s1 = *(const float4*)&sc[c + 4];
                float4 t0 = *(const float4*)&sh[c];
                float4 t1 = *(const float4*)&sh[c + 4];
                o0.x = f2bf(fmaxf(bf2f(h0.x) * s0.x + t0.x, 0.f));
                o0.y = f2bf(fmaxf(bf2f(h0.y) * s0.y + t0.y, 0.f));
                o0.z = f2bf(fmaxf(bf2f(h0.z) * s0.z + t0.z, 0.f));
                o0.w = f2bf(fmaxf(bf2f(h0.w) * s0.w + t0.w, 0.f));
                o1.x = f2bf(fmaxf(bf2f(h1v.x) * s1.x + t1.x, 0.f));
                o1.y = f2bf(fmaxf(bf2f(h1v.y) * s1.y + t1.y, 0.f));
                o1.z = f2bf(fmaxf(bf2f(h1v.z) * s1.z + t1.z, 0.f));
                o1.w = f2bf(fmaxf(bf2f(h1v.w) * s1.w + t1.w, 0.f));
            }
            *(ushort4*)&As[row * 40 + kc] = o0;
            *(ushort4*)&As[row * 40 + kc + 4] = o1;
            *(short8*)&Bs[row * 40 + kc] =
                *(const short8*)(W + (size_t)(bn + row) * K + k0 + kc);
        }
        __syncthreads();

        short8 af[4], bf[4];
#pragma unroll
        for (int sub = 0; sub < 4; sub++) {
            af[sub] = *(const short8*)&As[(r * 64 + sub * 16 + m16) * 40 + q * 8];
            bf[sub] = *(const short8*)&Bs[(cq * 64 + sub * 16 + m16) * 40 + q * 8];
        }
#pragma unroll
        for (int sm = 0; sm < 4; sm++)
#pragma unroll
            for (int sn = 0; sn < 4; sn++)
                acc[sm][sn] = __builtin_amdgcn_mfma_f32_16x16x32_bf16(
                    af[sm], bf[sn], acc[sm][sn], 0, 0, 0);
    }

    int row0 = bm + r * 64 + q * 4;
    int col0 = bn + cq * 64 + m16;
#pragma unroll
    for (int sm = 0; sm < 4; sm++)
#pragma unroll
        for (int sn = 0; sn < 4; sn++) {
            f32x4 v = acc[sm][sn];
#pragma unroll
            for (int reg = 0; reg < 4; reg++) {
                size_t idx = (size_t)(row0 + sm * 16 + reg) * 256 + col0 + sn * 16;
                if (MODE == 2) ((unsigned short*)Cv)[idx] = f2bf(v[reg]);
                else           ((float*)Cv)[idx] = v[reg];
            }
        }

    // ---- fused BN stats: per-block column sums of the 128x128 C tile ----
    __syncthreads();
    if (tid < 128) { colsum[tid] = 0.f; colsq[tid] = 0.f; }
    __syncthreads();
#pragma unroll
    for (int sn = 0; sn < 4; sn++) {
        float sacc = 0.f, qacc = 0.f;
#pragma unroll
        for (int sm = 0; sm < 4; sm++) {
            f32x4 v = acc[sm][sn];
#pragma unroll
            for (int reg = 0; reg < 4; reg++) {
                sacc += v[reg];
                qacc += v[reg] * v[reg];
            }
        }
        int lc = cq * 64 + sn * 16 + m16;
        atomicAdd(&colsum[lc], sacc);
        atomicAdd(&colsq[lc], qacc);
    }
    __syncthreads();
    if (tid < 128) {
        atomicAdd(&gsum[bn + tid], colsum[tid]);
        atomicAdd(&gsq[bn + tid], colsq[tid]);
    }
}

// --------- final: h2(ws) -> bn(raw sums, folded finalize)+relu -> d_out ---
__global__ __launch_bounds__(256) void final_act_kernel(
    const float* __restrict__ h2, const float* __restrict__ bnsum,
    const float* __restrict__ bnsq, const float* __restrict__ bng,
    const float* __restrict__ bnb, float invN,
    float* __restrict__ out, int total4)
{
    __shared__ float sc[256], sh[256];
    int c = threadIdx.x;
    float mean = bnsum[c] * invN;
    float var = bnsq[c] * invN - mean * mean;
    float scv = bng[c] * rsqrtf(var + BN_EPS);
    sc[c] = scv;
    sh[c] = bnb[c] - mean * scv;
    __syncthreads();

    int i = blockIdx.x * 256 + threadIdx.x;
    if (i >= total4) return;
    int c4 = i & 63;
    float4 v = ((const float4*)h2)[i];
    float4 s = *(const float4*)&sc[c4 * 4];
    float4 t = *(const float4*)&sh[c4 * 4];
    float4 o;
    o.x = fmaxf(v.x * s.x + t.x, 0.0f);
    o.y = fmaxf(v.y * s.y + t.y, 0.0f);
    o.z = fmaxf(v.z * s.z + t.z, 0.0f);
    o.w = fmaxf(v.w * s.w + t.w, 0.0f);
    ((float4*)out)[i] = o;
}

// ------------------------------------------------------------------ launch --
extern "C" void kernel_launch(void* const* d_in, const int* in_sizes, int n_in,
                              void* d_out, int out_size, void* d_ws, size_t ws_size,
                              hipStream_t stream)
{
    const float* unknown = (const float*)d_in[0];
    const int*   ucnt    = (const int*)d_in[1];
    const float* known   = (const float*)d_in[2];
    const int*   kcnt    = (const int*)d_in[3];
    const float* ufeat   = (const float*)d_in[4];
    const float* kfeat   = (const float*)d_in[5];
    const float* W1      = (const float*)d_in[6];
    const float* g1      = (const float*)d_in[7];
    const float* b1      = (const float*)d_in[8];
    const float* W2      = (const float*)d_in[9];
    const float* g2      = (const float*)d_in[10];
    const float* b2      = (const float*)d_in[11];

    int N = in_sizes[0] / 3;        // 65536
    int B = in_sizes[1];            // 4
    int M = in_sizes[2] / 3;        // 16384

    char* ws = (char*)d_ws;
    size_t off = 0;
    float* wgt = (float*)(ws + off);            off += (size_t)N * 3 * 4;
    int*   idxb = (int*)(ws + off);             off += (size_t)N * 3 * 4;
    float* stats = (float*)(ws + off);          off += 4 * 256 * 4;
    float* sum1 = stats,        *sq1 = stats + 256;
    float* sum2 = stats + 512,  *sq2 = stats + 768;
    // grid structures (cnt directly after stats -> one memset covers both)
    int* cnt = (int*)(ws + off);                off += (size_t)B * NB * 4;
    int* bsg = (int*)(ws + off);                off += ((size_t)B * NB + 1) * 4;
    int* cur = (int*)(ws + off);                off += (size_t)B * NB * 4;
    unsigned short* W1b = (unsigned short*)(ws + off);  off += 256 * 384 * 2;
    unsigned short* W2b = (unsigned short*)(ws + off);  off += 256 * 256 * 2;
    off = (off + 255) & ~(size_t)255;
    float4* scat = (float4*)(ws + off);         off += (size_t)M * sizeof(float4);
    off = (off + 255) & ~(size_t)255;
    unsigned short* h1 = (unsigned short*)(ws + off);   off += (size_t)N * 256 * 2;
    off = (off + 255) & ~(size_t)255;
    float* h2 = (float*)(ws + off);             // N*256 fp32 (67MB)

    float invN = 1.0f / (float)N;

    hipMemsetAsync(stats, 0, 4 * 256 * 4 + (size_t)B * NB * 4, stream);

    wconv_kernel<<<(256 * 384 + 256 * 256 + 255) / 256, 256, 0, stream>>>(
        W1, W2, W1b, W2b, 256 * 384, 256 * 256);

    hist_kernel<<<(M + 255) / 256, 256, 0, stream>>>(known, kcnt, B, M, cnt);
    scan_kernel<<<1, 1024, 0, stream>>>(cnt, bsg, cur, B * NB);
    scatter_kernel<<<(M + 255) / 256, 256, 0, stream>>>(known, kcnt, B, M, cur, scat);
    knn3_grid_kernel<<<N / 64, 256, 0, stream>>>(unknown, ucnt, bsg, scat,
                                                 B, wgt, idxb);

    gemm_bf16_kernel<384, 2><<<dim3(N / 128, 2), 256, 0, stream>>>(
        kfeat, ufeat, W1b, wgt, idxb,
        nullptr, nullptr, nullptr, nullptr, 0.f, h1, sum1, sq1);
    gemm_bf16_kernel<256, 1><<<dim3(N / 128, 2), 256, 0, stream>>>(
        h1, nullptr, W2b, nullptr, nullptr,
        sum1, sq1, g1, b1, invN, h2, sum2, sq2);
    final_act_kernel<<<N / 4, 256, 0, stream>>>(h2, sum2, sq2, g2, b2, invN,
                                                (float*)d_out, N * 64);
}

// Round 2
// 406.207 us; speedup vs baseline: 1.8964x; 1.8964x over previous
//
#include <hip/hip_runtime.h>
#include <math.h>

typedef __attribute__((ext_vector_type(8))) short short8;
typedef __attribute__((ext_vector_type(4))) float f32x4;

#define INF 3.0e38f
#define BN_EPS 1e-5f

// ---- x-bucket grid for 3-NN (exact; windowed cooperative scan) ----------
#define NB 1024            // buckets per batch along x
#define XMIN (-64.0f)
#define BW 0.125f          // bucket width
#define INVW 8.0f

__device__ __forceinline__ unsigned short f2bf(float x) {
    union { float f; unsigned u; } v; v.f = x;
    unsigned r = v.u + 0x7FFF + ((v.u >> 16) & 1);   // RNE
    return (unsigned short)(r >> 16);
}
__device__ __forceinline__ float bf2f(unsigned short u) {
    return __uint_as_float(((unsigned)u) << 16);
}

// ------------------------------------------------- grid: fused histogram --
// j < M: known point -> kc histogram; j >= M: unknown point -> qc histogram.
__global__ __launch_bounds__(256) void hist2_kernel(
    const float* __restrict__ kn, const int* __restrict__ kcnt, int M,
    const float* __restrict__ un, const int* __restrict__ ucnt, int N,
    int B, int* __restrict__ kc, int* __restrict__ qc)
{
    int j = blockIdx.x * 256 + threadIdx.x;
    const float* P; const int* C; int* out; int idx;
    if (j < M) { P = kn; C = kcnt; out = kc; idx = j; }
    else { idx = j - M; if (idx >= N) return; P = un; C = ucnt; out = qc; }
    int cum = 0, bb = 0;
    for (int i = 0; i < B; i++) { int c = C[i]; if (idx >= cum) bb = i; cum += c; }
    float x = P[idx * 3];
    int bi = (int)((x - XMIN) * INVW);
    bi = min(max(bi, 0), NB - 1);
    atomicAdd(&out[bb * NB + bi], 1);
}

// ------------------------- grid: exclusive scans (block 0: known, 1: unk) --
__global__ __launch_bounds__(1024) void scan2_kernel(
    const int* __restrict__ kc, int* __restrict__ kbs, int* __restrict__ kcur,
    const int* __restrict__ qc, int* __restrict__ qbs, int* __restrict__ qcur,
    int T)
{
    __shared__ int ts[1024];
    const int* cnt = blockIdx.x ? qc : kc;
    int* bs  = blockIdx.x ? qbs : kbs;
    int* cur = blockIdx.x ? qcur : kcur;

    int tid = threadIdx.x;
    int base = tid * 4;
    int v0 = 0, v1 = 0, v2 = 0, v3 = 0;
    if (base + 0 < T) v0 = cnt[base + 0];
    if (base + 1 < T) v1 = cnt[base + 1];
    if (base + 2 < T) v2 = cnt[base + 2];
    if (base + 3 < T) v3 = cnt[base + 3];
    int s = v0 + v1 + v2 + v3;
    ts[tid] = s;
    __syncthreads();
    for (int off = 1; off < 1024; off <<= 1) {
        int t = (tid >= off) ? ts[tid - off] : 0;
        __syncthreads();
        ts[tid] += t;
        __syncthreads();
    }
    int ex = ts[tid] - s;
    if (base + 0 < T) { bs[base + 0] = ex; cur[base + 0] = ex; } ex += v0;
    if (base + 1 < T) { bs[base + 1] = ex; cur[base + 1] = ex; } ex += v1;
    if (base + 2 < T) { bs[base + 2] = ex; cur[base + 2] = ex; } ex += v2;
    if (base + 3 < T) { bs[base + 3] = ex; cur[base + 3] = ex; } ex += v3;
    if (tid == ((T - 1) >> 2)) bs[T] = ts[tid];
}

// --------------------------------------------------- grid: fused scatter --
// stores float4 {x, y, z, bits(globalIdx)} bucket-sorted, per-batch blocks.
__global__ __launch_bounds__(256) void scatter2_kernel(
    const float* __restrict__ kn, const int* __restrict__ kcnt, int M,
    const float* __restrict__ un, const int* __restrict__ ucnt, int N,
    int B, int* __restrict__ kcur, float4* __restrict__ kscat,
    int* __restrict__ qcur, float4* __restrict__ qscat)
{
    int j = blockIdx.x * 256 + threadIdx.x;
    const float* P; const int* C; int* cur; float4* out; int idx;
    if (j < M) { P = kn; C = kcnt; cur = kcur; out = kscat; idx = j; }
    else { idx = j - M; if (idx >= N) return; P = un; C = ucnt; cur = qcur; out = qscat; }
    int cum = 0, bb = 0;
    for (int i = 0; i < B; i++) { int c = C[i]; if (idx >= cum) bb = i; cum += c; }
    float x = P[idx * 3], y = P[idx * 3 + 1], z = P[idx * 3 + 2];
    int bi = (int)((x - XMIN) * INVW);
    bi = min(max(bi, 0), NB - 1);
    int pos = atomicAdd(&cur[bb * NB + bi], 1);
    out[pos] = make_float4(x, y, z, __int_as_float(idx));
}

// ---------------------------------------------------------------- 3-NN ----
// Sorted queries: block = 64 spatially-adjacent queries, 4 waves.
// Phase A: 32 x-nearest candidates per query (8 per wave, value-only top-3,
//   LDS merge) -> thr >= true d3 (3rd-smallest of subset >= of full set).
// Window: buckets within +-(sqrt(thr)+2*BW) -> contains all true 3-NN
//   (any excluded candidate has dx > sqrt(thr) => e > thr >= d3 strictly).
// Phase B: wave-union window, exact quarter partition on 8-chunks, uniform
//   s_load candidate stream (r0's scalar-pipe pattern), min-8 screen, u64
//   (f32bits<<32|idx) lex inserts == lax.top_k bit-exact; thr tightens
//   monotonically (screen-out => e > current-3rd >= final-3rd, strict).
__global__ __launch_bounds__(256) void knn3_grid2_kernel(
    const int* __restrict__ ucnt, const int* __restrict__ kbs,
    const float4* __restrict__ qscat, const float4* __restrict__ scat,
    int B, float* __restrict__ wgt, int* __restrict__ idxo)
{
    __shared__ float md[4][64][3];
    __shared__ unsigned long long mk[64][4][3];

    int tid = threadIdx.x;
    int wv = tid >> 6;
    int lane = tid & 63;
    int pbase = blockIdx.x * 64;
    int qpos = pbase + lane;

    // batch id of this block's queries (sorted layout is per-batch blocks;
    // per-batch counts are multiples of 64 here)
    int cum = 0, bb = 0;
    for (int i = 0; i < B; i++) { int c = ucnt[i]; if (pbase >= cum) bb = i; cum += c; }

    float4 qf = qscat[qpos];
    float ux = qf.x, uy = qf.y, uz = qf.z;

    int kst = kbs[bb * NB];
    int ken = kbs[bb * NB + NB];

    // ---------------- phase A: bound from 32 x-nearest (8 per wave) -------
    int bq = (int)((ux - XMIN) * INVW);
    bq = min(max(bq, 0), NB - 1);
    int sp = kbs[bb * NB + bq];
    int lo = sp - 16;
    if (lo < kst) lo = kst;
    if (lo + 32 > ken) lo = ken - 32;
    if (lo < kst) lo = kst;

    float d0 = INF, d1 = INF, d2v = INF;
    int alo = lo + wv * 8;
    int ahi = min(alo + 8, ken);
    for (int c = alo; c < ahi; c++) {
        float4 f = scat[c];
        float dx = f.x - ux, dy = f.y - uy, dz = f.z - uz;
        float e = __builtin_fmaf(dx, dx, __builtin_fmaf(dy, dy, dz * dz));
        float m0 = fmaxf(e, d0), m1 = fmaxf(e, d1);
        d0 = fminf(e, d0); d1 = fminf(m0, d1); d2v = fminf(m1, d2v);
    }
    md[wv][lane][0] = d0; md[wv][lane][1] = d1; md[wv][lane][2] = d2v;
    __syncthreads();

    d0 = INF; d1 = INF; d2v = INF;
#pragma unroll
    for (int w = 0; w < 4; w++)
#pragma unroll
        for (int k = 0; k < 3; k++) {
            float e = md[w][lane][k];
            float m0 = fmaxf(e, d0), m1 = fmaxf(e, d1);
            d0 = fminf(e, d0); d1 = fminf(m0, d1); d2v = fminf(m1, d2v);
        }
    float thr = d2v;

    // ---------------- window from bound -----------------------------------
    float W = fminf(sqrtf(thr), 300.0f);     // guard INF (tiny batches)
    int blo = max((int)((ux - W - XMIN) * INVW) - 1, 0);
    int bhi = min((int)((ux + W - XMIN) * INVW) + 1, NB - 1);
    int pLo = kbs[bb * NB + blo];
    int pHi = kbs[bb * NB + bhi + 1];

    int wlo = pLo, whi = pHi;
#pragma unroll
    for (int s = 1; s < 64; s <<= 1) {
        wlo = min(wlo, __shfl_xor(wlo, s, 64));
        whi = max(whi, __shfl_xor(whi, s, 64));
    }

    // exact quarter partition on 8-candidate chunks
    int chunks = (whi - wlo + 7) >> 3;
    int cpw = (chunks + 3) >> 2;
    int c0 = min(wv * cpw, chunks);
    int c1 = min(c0 + cpw, chunks);
    int mylo = wlo + (c0 << 3);
    int myhi = min(wlo + (c1 << 3), whi);
    mylo = __builtin_amdgcn_readfirstlane(mylo);
    myhi = __builtin_amdgcn_readfirstlane(myhi);

    // ---------------- phase B: screened selection over own quarter --------
    unsigned long long k0 = ~0ULL, k1 = ~0ULL, k2 = ~0ULL;
    auto insK = [&](unsigned long long k) {
        bool cc0 = k < k0;
        unsigned long long t0 = cc0 ? k : k0;
        unsigned long long t1 = cc0 ? k0 : k;
        bool cc1 = t1 < k1;
        unsigned long long u0 = cc1 ? t1 : k1;
        unsigned long long u1 = cc1 ? k1 : t1;
        k0 = t0; k1 = u0;
        k2 = u1 < k2 ? u1 : k2;
    };

    const float4* kq = scat + mylo;     // uniform base -> scalar loads
    int n = myhi - mylo;
    int nf = n & ~7;
    for (int i = 0; i < nf; i += 8) {
        float ex[8]; int ix[8];
#pragma unroll
        for (int c = 0; c < 8; c++) {
            float4 f = kq[i + c];
            float dx = f.x - ux, dy = f.y - uy, dz = f.z - uz;
            ex[c] = __builtin_fmaf(dx, dx, __builtin_fmaf(dy, dy, dz * dz));
            ix[c] = __float_as_int(f.w);
        }
        float m8 = fminf(fminf(fminf(ex[0], ex[1]), fminf(ex[2], ex[3])),
                         fminf(fminf(ex[4], ex[5]), fminf(ex[6], ex[7])));
        if (m8 <= thr) {
#pragma unroll
            for (int c = 0; c < 8; c++) {
                if (ex[c] <= thr) {
                    insK(((unsigned long long)__float_as_uint(ex[c]) << 32) |
                         (unsigned)ix[c]);
                    thr = fminf(thr, __uint_as_float((unsigned)(k2 >> 32)));
                }
            }
        }
    }
    for (int i = nf; i < n; i++) {      // remainder (<8)
        float4 f = kq[i];
        float dx = f.x - ux, dy = f.y - uy, dz = f.z - uz;
        float e = __builtin_fmaf(dx, dx, __builtin_fmaf(dy, dy, dz * dz));
        if (e <= thr) {
            insK(((unsigned long long)__float_as_uint(e) << 32) |
                 (unsigned)__float_as_int(f.w));
            thr = fminf(thr, __uint_as_float((unsigned)(k2 >> 32)));
        }
    }

    mk[lane][wv][0] = k0; mk[lane][wv][1] = k1; mk[lane][wv][2] = k2;
    __syncthreads();

    if (tid < 64) {
        unsigned long long a0 = ~0ULL, a1 = ~0ULL, a2 = ~0ULL;
        auto ins2 = [&](unsigned long long k) {
            bool cc0 = k < a0;
            unsigned long long t0 = cc0 ? k : a0;
            unsigned long long t1 = cc0 ? a0 : k;
            bool cc1 = t1 < a1;
            unsigned long long u0 = cc1 ? t1 : a1;
            unsigned long long u1 = cc1 ? a1 : t1;
            a0 = t0; a1 = u0;
            a2 = u1 < a2 ? u1 : a2;
        };
#pragma unroll
        for (int r = 0; r < 4; r++)
#pragma unroll
            for (int kk = 0; kk < 3; kk++)
                ins2(mk[tid][r][kk]);

        float dd0 = __uint_as_float((unsigned)(a0 >> 32));
        float dd1 = __uint_as_float((unsigned)(a1 >> 32));
        float dd2 = __uint_as_float((unsigned)(a2 >> 32));
        float r0 = 1.0f / (dd0 + 1e-8f);
        float r1 = 1.0f / (dd1 + 1e-8f);
        float r2 = 1.0f / (dd2 + 1e-8f);
        float rs = 1.0f / (r0 + r1 + r2);
        int orig = __float_as_int(qscat[pbase + tid].w);
        wgt[orig * 3 + 0] = r0 * rs;
        wgt[orig * 3 + 1] = r1 * rs;
        wgt[orig * 3 + 2] = r2 * rs;
        idxo[orig * 3 + 0] = (int)(unsigned)a0;
        idxo[orig * 3 + 1] = (int)(unsigned)a1;
        idxo[orig * 3 + 2] = (int)(unsigned)a2;
    }
}

// ------------------------------------------------ weight fp32->bf16 conv --
__global__ __launch_bounds__(256) void wconv_kernel(
    const float* __restrict__ W1, const float* __restrict__ W2,
    unsigned short* __restrict__ W1b, unsigned short* __restrict__ W2b,
    int n1, int n2)
{
    int i = blockIdx.x * 256 + threadIdx.x;
    if (i < n1) W1b[i] = f2bf(W1[i]);
    int j = i - n1;
    if (j >= 0 && j < n2) W2b[j] = f2bf(W2[j]);
}

// -------------------------------------------------------- bf16 MFMA GEMM --
// C[N,256] = A[N,K] x W[256,K]^T.  128x128 tile, BK=32, 16x16x32 MFMA.
// MODE 2 (gemm1): A materialized on the fly in staging (interp cols 0..255
//   gathered from kfeat via wgt/idx; ufeat cols 256..383). C stored as BF16
//   (h1) — BN1 stats come from fp32 accumulators, exact.
// MODE 1 (gemm2): A = relu(h1_bf16*scale+shift) -> bf16; scale/shift computed
//   in a 256-thread LDS prologue from raw BN sums (bn_finalize folded in).
//   C stored fp32 (h2).
// Fused epilogue: per-block column sum/sumsq of C -> global atomics.
template <int K, int MODE>
__global__ __launch_bounds__(256) void gemm_bf16_kernel(
    const void* __restrict__ Aa, const float* __restrict__ ufeat,
    const unsigned short* __restrict__ W,
    const float* __restrict__ wgt, const int* __restrict__ idxv,
    const float* __restrict__ bnsum, const float* __restrict__ bnsq,
    const float* __restrict__ bng, const float* __restrict__ bnb, float invN,
    void* __restrict__ Cv, float* __restrict__ gsum, float* __restrict__ gsq)
{
    __shared__ unsigned short As[128 * 40];
    __shared__ unsigned short Bs[128 * 40];
    __shared__ float colsum[128];
    __shared__ float colsq[128];
    __shared__ float sc[256], sh[256];

    int tid = threadIdx.x;
    int w = tid >> 6, lane = tid & 63;
    int r = w >> 1, cq = w & 1;
    int m16 = lane & 15, q = lane >> 4;
    int bm = blockIdx.x * 128, bn = blockIdx.y * 128;

    if (MODE == 1) {            // fold bn_finalize: per-channel scale/shift
        float mean = bnsum[tid] * invN;
        float var = bnsq[tid] * invN - mean * mean;
        float scv = bng[tid] * rsqrtf(var + BN_EPS);
        sc[tid] = scv;
        sh[tid] = bnb[tid] - mean * scv;
    }

    // per-thread staging slots: rows srow, srow+64 with fixed 8-ch chunk kc
    int srow = tid >> 2;
    int kc = (tid & 3) * 8;
    float w0a[2], w1a[2], w2a[2];
    int j0a[2], j1a[2], j2a[2];
    if (MODE == 2) {
#pragma unroll
        for (int t = 0; t < 2; t++) {
            int pp = bm + srow + 64 * t;
            w0a[t] = wgt[pp * 3 + 0]; w1a[t] = wgt[pp * 3 + 1]; w2a[t] = wgt[pp * 3 + 2];
            j0a[t] = idxv[pp * 3 + 0]; j1a[t] = idxv[pp * 3 + 1]; j2a[t] = idxv[pp * 3 + 2];
        }
    }

    f32x4 acc[4][4];
#pragma unroll
    for (int i = 0; i < 4; i++)
#pragma unroll
        for (int j = 0; j < 4; j++) acc[i][j] = (f32x4){0.f, 0.f, 0.f, 0.f};

#pragma unroll
    for (int k0 = 0; k0 < K; k0 += 32) {
        __syncthreads();
#pragma unroll
        for (int t = 0; t < 2; t++) {
            int row = srow + 64 * t;
            int c = k0 + kc;
            ushort4 o0, o1;
            if (MODE == 2) {
                if (c < 256) {          // interp cols (compile-time per iter)
                    const float* f0 = (const float*)Aa + (size_t)j0a[t] * 256 + c;
                    const float* f1 = (const float*)Aa + (size_t)j1a[t] * 256 + c;
                    const float* f2 = (const float*)Aa + (size_t)j2a[t] * 256 + c;
                    float4 x0 = *(const float4*)f0, x1 = *(const float4*)(f0 + 4);
                    float4 y0 = *(const float4*)f1, y1 = *(const float4*)(f1 + 4);
                    float4 z0 = *(const float4*)f2, z1 = *(const float4*)(f2 + 4);
                    float W0 = w0a[t], W1 = w1a[t], W2 = w2a[t];
                    o0.x = f2bf(x0.x * W0 + y0.x * W1 + z0.x * W2);
                    o0.y = f2bf(x0.y * W0 + y0.y * W1 + z0.y * W2);
                    o0.z = f2bf(x0.z * W0 + y0.z * W1 + z0.z * W2);
                    o0.w = f2bf(x0.w * W0 + y0.w * W1 + z0.w * W2);
                    o1.x = f2bf(x1.x * W0 + y1.x * W1 + z1.x * W2);
                    o1.y = f2bf(x1.y * W0 + y1.y * W1 + z1.y * W2);
                    o1.z = f2bf(x1.z * W0 + y1.z * W1 + z1.z * W2);
                    o1.w = f2bf(x1.w * W0 + y1.w * W1 + z1.w * W2);
                } else {                // ufeat cols
                    const float* fu = ufeat + (size_t)(bm + row) * 128 + (c - 256);
                    float4 u0 = *(const float4*)fu, u1 = *(const float4*)(fu + 4);
                    o0.x = f2bf(u0.x); o0.y = f2bf(u0.y);
                    o0.z = f2bf(u0.z); o0.w = f2bf(u0.w);
                    o1.x = f2bf(u1.x); o1.y = f2bf(u1.y);
                    o1.z = f2bf(u1.z); o1.w = f2bf(u1.w);
                }
            } else {                    // MODE 1: bn+relu+bf16 from bf16 h1
                const unsigned short* Ab = (const unsigned short*)Aa;
                ushort4 h0 = *(const ushort4*)(Ab + (size_t)(bm + row) * K + c);
                ushort4 h1v = *(const ushort4*)(Ab + (size_t)(bm + row) * K + c + 4);
                float4 s0 = *(const float4*)&sc[c];
                float4 s1 = *(const float4*)&sc[c + 4];
                float4 t0 = *(const float4*)&sh[c];
                float4 t1 = *(const float4*)&sh[c + 4];
                o0.x = f2bf(fmaxf(bf2f(h0.x) * s0.x + t0.x, 0.f));
                o0.y = f2bf(fmaxf(bf2f(h0.y) * s0.y + t0.y, 0.f));
                o0.z = f2bf(fmaxf(bf2f(h0.z) * s0.z + t0.z, 0.f));
                o0.w = f2bf(fmaxf(bf2f(h0.w) * s0.w + t0.w, 0.f));
                o1.x = f2bf(fmaxf(bf2f(h1v.x) * s1.x + t1.x, 0.f));
                o1.y = f2bf(fmaxf(bf2f(h1v.y) * s1.y + t1.y, 0.f));
                o1.z = f2bf(fmaxf(bf2f(h1v.z) * s1.z + t1.z, 0.f));
                o1.w = f2bf(fmaxf(bf2f(h1v.w) * s1.w + t1.w, 0.f));
            }
            *(ushort4*)&As[row * 40 + kc] = o0;
            *(ushort4*)&As[row * 40 + kc + 4] = o1;
            *(short8*)&Bs[row * 40 + kc] =
                *(const short8*)(W + (size_t)(bn + row) * K + k0 + kc);
        }
        __syncthreads();

        short8 af[4], bf[4];
#pragma unroll
        for (int sub = 0; sub < 4; sub++) {
            af[sub] = *(const short8*)&As[(r * 64 + sub * 16 + m16) * 40 + q * 8];
            bf[sub] = *(const short8*)&Bs[(cq * 64 + sub * 16 + m16) * 40 + q * 8];
        }
#pragma unroll
        for (int sm = 0; sm < 4; sm++)
#pragma unroll
            for (int sn = 0; sn < 4; sn++)
                acc[sm][sn] = __builtin_amdgcn_mfma_f32_16x16x32_bf16(
                    af[sm], bf[sn], acc[sm][sn], 0, 0, 0);
    }

    int row0 = bm + r * 64 + q * 4;
    int col0 = bn + cq * 64 + m16;
#pragma unroll
    for (int sm = 0; sm < 4; sm++)
#pragma unroll
        for (int sn = 0; sn < 4; sn++) {
            f32x4 v = acc[sm][sn];
#pragma unroll
            for (int reg = 0; reg < 4; reg++) {
                size_t idx = (size_t)(row0 + sm * 16 + reg) * 256 + col0 + sn * 16;
                if (MODE == 2) ((unsigned short*)Cv)[idx] = f2bf(v[reg]);
                else           ((float*)Cv)[idx] = v[reg];
            }
        }

    // ---- fused BN stats: per-block column sums of the 128x128 C tile ----
    __syncthreads();
    if (tid < 128) { colsum[tid] = 0.f; colsq[tid] = 0.f; }
    __syncthreads();
#pragma unroll
    for (int sn = 0; sn < 4; sn++) {
        float sacc = 0.f, qacc = 0.f;
#pragma unroll
        for (int sm = 0; sm < 4; sm++) {
            f32x4 v = acc[sm][sn];
#pragma unroll
            for (int reg = 0; reg < 4; reg++) {
                sacc += v[reg];
                qacc += v[reg] * v[reg];
            }
        }
        int lc = cq * 64 + sn * 16 + m16;
        atomicAdd(&colsum[lc], sacc);
        atomicAdd(&colsq[lc], qacc);
    }
    __syncthreads();
    if (tid < 128) {
        atomicAdd(&gsum[bn + tid], colsum[tid]);
        atomicAdd(&gsq[bn + tid], colsq[tid]);
    }
}

// --------- final: h2(ws) -> bn(raw sums, folded finalize)+relu -> d_out ---
__global__ __launch_bounds__(256) void final_act_kernel(
    const float* __restrict__ h2, const float* __restrict__ bnsum,
    const float* __restrict__ bnsq, const float* __restrict__ bng,
    const float* __restrict__ bnb, float invN,
    float* __restrict__ out, int total4)
{
    __shared__ float sc[256], sh[256];
    int c = threadIdx.x;
    float mean = bnsum[c] * invN;
    float var = bnsq[c] * invN - mean * mean;
    float scv = bng[c] * rsqrtf(var + BN_EPS);
    sc[c] = scv;
    sh[c] = bnb[c] - mean * scv;
    __syncthreads();

    int i = blockIdx.x * 256 + threadIdx.x;
    if (i >= total4) return;
    int c4 = i & 63;
    float4 v = ((const float4*)h2)[i];
    float4 s = *(const float4*)&sc[c4 * 4];
    float4 t = *(const float4*)&sh[c4 * 4];
    float4 o;
    o.x = fmaxf(v.x * s.x + t.x, 0.0f);
    o.y = fmaxf(v.y * s.y + t.y, 0.0f);
    o.z = fmaxf(v.z * s.z + t.z, 0.0f);
    o.w = fmaxf(v.w * s.w + t.w, 0.0f);
    ((float4*)out)[i] = o;
}

// ------------------------------------------------------------------ launch --
extern "C" void kernel_launch(void* const* d_in, const int* in_sizes, int n_in,
                              void* d_out, int out_size, void* d_ws, size_t ws_size,
                              hipStream_t stream)
{
    const float* unknown = (const float*)d_in[0];
    const int*   ucnt    = (const int*)d_in[1];
    const float* known   = (const float*)d_in[2];
    const int*   kcnt    = (const int*)d_in[3];
    const float* ufeat   = (const float*)d_in[4];
    const float* kfeat   = (const float*)d_in[5];
    const float* W1      = (const float*)d_in[6];
    const float* g1      = (const float*)d_in[7];
    const float* b1      = (const float*)d_in[8];
    const float* W2      = (const float*)d_in[9];
    const float* g2      = (const float*)d_in[10];
    const float* b2      = (const float*)d_in[11];

    int N = in_sizes[0] / 3;        // 65536
    int B = in_sizes[1];            // 4
    int M = in_sizes[2] / 3;        // 16384
    int T = B * NB;

    char* ws = (char*)d_ws;
    size_t off = 0;
    float* wgt = (float*)(ws + off);            off += (size_t)N * 3 * 4;
    int*   idxb = (int*)(ws + off);             off += (size_t)N * 3 * 4;
    float* stats = (float*)(ws + off);          off += 4 * 256 * 4;
    float* sum1 = stats,        *sq1 = stats + 256;
    float* sum2 = stats + 512,  *sq2 = stats + 768;
    // histograms directly after stats -> one memset covers stats+kch+qch
    int* kch = (int*)(ws + off);                off += (size_t)T * 4;
    int* qch = (int*)(ws + off);                off += (size_t)T * 4;
    int* kbs = (int*)(ws + off);                off += ((size_t)T + 1) * 4;
    int* qbs = (int*)(ws + off);                off += ((size_t)T + 1) * 4;
    int* kcur = (int*)(ws + off);               off += (size_t)T * 4;
    int* qcur = (int*)(ws + off);               off += (size_t)T * 4;
    unsigned short* W1b = (unsigned short*)(ws + off);  off += 256 * 384 * 2;
    unsigned short* W2b = (unsigned short*)(ws + off);  off += 256 * 256 * 2;
    off = (off + 255) & ~(size_t)255;
    float4* kscat = (float4*)(ws + off);        off += (size_t)M * sizeof(float4);
    float4* qscat = (float4*)(ws + off);        off += (size_t)N * sizeof(float4);
    off = (off + 255) & ~(size_t)255;
    unsigned short* h1 = (unsigned short*)(ws + off);   off += (size_t)N * 256 * 2;
    off = (off + 255) & ~(size_t)255;
    float* h2 = (float*)(ws + off);             // N*256 fp32 (67MB)

    float invN = 1.0f / (float)N;

    hipMemsetAsync(stats, 0, 4 * 256 * 4 + 2 * (size_t)T * 4, stream);

    wconv_kernel<<<(256 * 384 + 256 * 256 + 255) / 256, 256, 0, stream>>>(
        W1, W2, W1b, W2b, 256 * 384, 256 * 256);

    hist2_kernel<<<(M + N + 255) / 256, 256, 0, stream>>>(
        known, kcnt, M, unknown, ucnt, N, B, kch, qch);
    scan2_kernel<<<2, 1024, 0, stream>>>(kch, kbs, kcur, qch, qbs, qcur, T);
    scatter2_kernel<<<(M + N + 255) / 256, 256, 0, stream>>>(
        known, kcnt, M, unknown, ucnt, N, B, kcur, kscat, qcur, qscat);
    knn3_grid2_kernel<<<N / 64, 256, 0, stream>>>(ucnt, kbs, qscat, kscat,
                                                  B, wgt, idxb);

    gemm_bf16_kernel<384, 2><<<dim3(N / 128, 2), 256, 0, stream>>>(
        kfeat, ufeat, W1b, wgt, idxb,
        nullptr, nullptr, nullptr, nullptr, 0.f, h1, sum1, sq1);
    gemm_bf16_kernel<256, 1><<<dim3(N / 128, 2), 256, 0, stream>>>(
        h1, nullptr, W2b, nullptr, nullptr,
        sum1, sq1, g1, b1, invN, h2, sum2, sq2);
    final_act_kernel<<<N / 4, 256, 0, stream>>>(h2, sum2, sq2, g2, b2, invN,
                                                (float*)d_out, N * 64);
}